// Round 1
// baseline (363.412 us; speedup 1.0000x reference)
//
#include <hip/hip_runtime.h>
#include <cstdint>

// MemNet restructure: all hops reduced to scalar recursions over
// Q[b,l,j] = v_loc[b,l] * (mem[b,l] . M_j),  25 projection columns:
//   col 0        : w0 = w_attn[0:D]          (scores)
//   col 1+k      : U_k = W_lin^k u, k=0..5   (u = w_attn[D:2D])
//   col 7+6c+k   : Y_{k,c} = W_lin^k W_out[:,c], k=0..5
//   col 25+c     : Y_{6,c}  (only dotted with v_aspect)
// ws: Mt [1024][32] row-major (for sgpr loads in gemm), Mc [32][1024]
// col-major (for coalesced chain/hop reads), Q [64][25][512].

#define DD 1024
#define LL 512
#define BB 64
#define MTS 32

__global__ __launch_bounds__(256) void k_init(const float* __restrict__ w_attn,
                                              const float* __restrict__ W_out,
                                              float* __restrict__ Mt,
                                              float* __restrict__ Mc)
{
  int d = blockIdx.x * 256 + threadIdx.x;  // 4 blocks -> d in [0,1024)
  float w0 = w_attn[d];
  float u0 = w_attn[DD + d];
  Mt[d * MTS + 0] = w0; Mc[0 * DD + d] = w0;
  Mt[d * MTS + 1] = u0; Mc[1 * DD + d] = u0;
#pragma unroll
  for (int c = 0; c < 3; ++c) {
    float y = W_out[d * 3 + c];
    int col = 7 + 6 * c;
    Mt[d * MTS + col] = y; Mc[col * DD + d] = y;
  }
}

// one chain step: out[i] = sum_j W[i][j] * in[j] for up to 4 column pairs
__global__ __launch_bounds__(256) void k_chain(const float* __restrict__ Wl,
                                               float* __restrict__ Mt,
                                               float* __restrict__ Mc,
                                               int i0, int i1, int i2, int i3,
                                               int o0, int o1, int o2, int o3)
{
  int tid = threadIdx.x;
  int wv = __builtin_amdgcn_readfirstlane(tid >> 6);
  int ln = tid & 63;
  int i = blockIdx.x * 4 + wv;  // 256 blocks -> i in [0,1024)
  const float* wrow = Wl + (size_t)i * DD;
  int c0 = i0 < 0 ? 0 : i0, c1 = i1 < 0 ? 0 : i1;
  int c2 = i2 < 0 ? 0 : i2, c3 = i3 < 0 ? 0 : i3;
  float s0 = 0.f, s1 = 0.f, s2 = 0.f, s3 = 0.f;
  for (int m = 0; m < 16; ++m) {
    int j = ln + m * 64;
    float w = wrow[j];
    s0 += w * Mc[c0 * DD + j];
    s1 += w * Mc[c1 * DD + j];
    s2 += w * Mc[c2 * DD + j];
    s3 += w * Mc[c3 * DD + j];
  }
#pragma unroll
  for (int m = 1; m < 64; m <<= 1) {
    s0 += __shfl_xor(s0, m, 64); s1 += __shfl_xor(s1, m, 64);
    s2 += __shfl_xor(s2, m, 64); s3 += __shfl_xor(s3, m, 64);
  }
  if (ln == 0) {
    if (o0 >= 0) { Mt[i * MTS + o0] = s0; Mc[o0 * DD + i] = s0; }
    if (o1 >= 0) { Mt[i * MTS + o1] = s1; Mc[o1 * DD + i] = s1; }
    if (o2 >= 0) { Mt[i * MTS + o2] = s2; Mc[o2 * DD + i] = s2; }
    if (o3 >= 0) { Mt[i * MTS + o3] = s3; Mc[o3 * DD + i] = s3; }
  }
}

// Q[b][j][l] = v_loc * (emb[ctx_ids[b*512+l]] . Mt col j), j<25
// 512 blocks x 256 thr: block = 64 consecutive rows; wave kq handles k-quarter.
__global__ __launch_bounds__(256, 2) void k_gemm(const int* __restrict__ ctx_ids,
                                                 const int* __restrict__ ctx_len,
                                                 const int* __restrict__ toff,
                                                 const float* __restrict__ emb,
                                                 const float* __restrict__ Mt,
                                                 float* __restrict__ Q)
{
  __shared__ float stag[4][64 * 33];   // per-wave staging, stride 33 (2-way only)
  __shared__ float qp[4][64][25];      // per-wave partial Q
  int tid = threadIdx.x;
  int kq = __builtin_amdgcn_readfirstlane(tid >> 6);
  int ln = tid & 63;
  int rowbase = blockIdx.x * 64;
  int myid = ctx_ids[rowbase + ln];
  const float* base[8];
#pragma unroll
  for (int ii = 0; ii < 8; ++ii) {
    int rid = __shfl(myid, ii * 8 + (ln >> 3), 64);
    base[ii] = emb + (size_t)rid * DD;
  }
  int p4 = (ln & 7) * 4;
  float* sw = stag[kq];
  int k0 = kq * 256;
  float acc[25];
#pragma unroll
  for (int j = 0; j < 25; ++j) acc[j] = 0.f;

  float4 buf[8];
#pragma unroll
  for (int ii = 0; ii < 8; ++ii)
    buf[ii] = *(const float4*)(base[ii] + k0 + p4);

  for (int ch = 0; ch < 8; ++ch) {
    // staging: lane writes row r = ii*8 + (ln>>3), float4 slot p = ln&7
#pragma unroll
    for (int ii = 0; ii < 8; ++ii) {
      int r = ii * 8 + (ln >> 3);
      int a = r * 33 + p4;
      sw[a + 0] = buf[ii].x; sw[a + 1] = buf[ii].y;
      sw[a + 2] = buf[ii].z; sw[a + 3] = buf[ii].w;
    }
    if (ch < 7) {
      int kb = k0 + (ch + 1) * 32;
#pragma unroll
      for (int ii = 0; ii < 8; ++ii)
        buf[ii] = *(const float4*)(base[ii] + kb + p4);
    }
    __builtin_amdgcn_s_waitcnt(0xc07f);  // lgkmcnt(0): writes visible (same-wave sharing)
    const float* mrow = Mt + (size_t)(k0 + ch * 32) * MTS;  // wave-uniform -> s_load
#pragma unroll 4
    for (int kk = 0; kk < 32; ++kk) {
      float mv = sw[ln * 33 + kk];   // lane = row
#pragma unroll
      for (int j = 0; j < 25; ++j) acc[j] += mv * mrow[kk * MTS + j];
    }
  }
#pragma unroll
  for (int j = 0; j < 25; ++j) qp[kq][ln][j] = acc[j];
  __syncthreads();

  int b = rowbase >> 9;
  int l0 = rowbase & 511;
  int clen = ctx_len[b];
  int off = toff[b];
  float fclen = (float)clen;
  for (int i = tid; i < 1600; i += 256) {
    int j = i >> 6, r = i & 63;
    float s = qp[0][r][j] + qp[1][r][j] + qp[2][r][j] + qp[3][r][j];
    int l = l0 + r;
    float vl = (l < clen) ? (1.f - fabsf((float)(l - off)) / fclen) : 0.f;
    Q[((size_t)b * 25 + j) * LL + l] = s * vl;
  }
}

template <bool ISMAX>
__device__ __forceinline__ void breduce(float* v, int n, float* lds, int tid)
{
  int wv = __builtin_amdgcn_readfirstlane(tid >> 6);
  int ln = tid & 63;
  for (int q = 0; q < n; ++q) {
    float x = v[q];
#pragma unroll
    for (int m = 1; m < 64; m <<= 1) {
      float o = __shfl_xor(x, m, 64);
      x = ISMAX ? fmaxf(x, o) : x + o;
    }
    if (ln == 0) lds[q * 4 + wv] = x;
  }
  __syncthreads();
  for (int q = 0; q < n; ++q) {
    float a = lds[q * 4 + 0], b = lds[q * 4 + 1];
    float c = lds[q * 4 + 2], d = lds[q * 4 + 3];
    v[q] = ISMAX ? fmaxf(fmaxf(a, b), fmaxf(c, d)) : ((a + b) + (c + d));
  }
  __syncthreads();
}

// one block per batch: v_aspect dots, then 6 hops in scalar space, write logits
__global__ __launch_bounds__(256) void k_hop(const int* __restrict__ tgt_ids,
                                             const int* __restrict__ tgt_len,
                                             const int* __restrict__ ctx_len,
                                             const float* __restrict__ emb,
                                             const float* __restrict__ b_lin,
                                             const float* __restrict__ b_attn,
                                             const float* __restrict__ b_out,
                                             const float* __restrict__ Mc,
                                             const float* __restrict__ Q,
                                             float* __restrict__ out)
{
  __shared__ float Qs[25 * LL];   // 51.2 KB
  __shared__ float va[DD];
  __shared__ float red[36 * 4];
  int tid = threadIdx.x;
  int b = blockIdx.x;

  for (int i = tid; i < 25 * LL; i += 256) Qs[i] = Q[(size_t)b * (25 * LL) + i];

  int tl = tgt_len[b];
  float inv_tl = 1.f / (float)tl;
  for (int d = tid; d < DD; d += 256) {
    float s = 0.f;
#pragma unroll
    for (int t = 0; t < 8; ++t)
      if (t < tl) s += emb[(size_t)tgt_ids[b * 8 + t] * DD + d];
    va[d] = s * inv_tl;
  }
  __syncthreads();

  // 32 dots: p[0..5]=va.U_k, p[6..8]=va.Y6c, p[9..13]=b.U_k(k<5), p[14+6c+k]=b.Y_{k,c}
  float p[32];
#pragma unroll
  for (int q = 0; q < 32; ++q) p[q] = 0.f;
  for (int d = tid; d < DD; d += 256) {
    float vad = va[d], bd = b_lin[d];
#pragma unroll
    for (int k = 0; k < 6; ++k) {
      float u = Mc[(1 + k) * DD + d];
      p[k] += vad * u;
      if (k < 5) p[9 + k] += bd * u;
    }
#pragma unroll
    for (int c = 0; c < 3; ++c) {
      p[6 + c] += vad * Mc[(25 + c) * DD + d];
#pragma unroll
      for (int k = 0; k < 6; ++k)
        p[14 + c * 6 + k] += bd * Mc[(7 + 6 * c + k) * DD + d];
    }
  }
  breduce<false>(p, 32, red, tid);

  float tcur[6], rc[3], beta[5], gam[18];
#pragma unroll
  for (int k = 0; k < 6; ++k) tcur[k] = p[k];
#pragma unroll
  for (int c = 0; c < 3; ++c) rc[c] = p[6 + c];
#pragma unroll
  for (int k = 0; k < 5; ++k) beta[k] = p[9 + k];
#pragma unroll
  for (int q = 0; q < 18; ++q) gam[q] = p[14 + q];

  int clen = ctx_len[b];
  float batt = b_attn[0];
  int l1 = tid, l2 = tid + 256;

  for (int h = 0; h < 6; ++h) {
    float s_h = tcur[0];
    float sc1 = -1e30f, sc2 = -1e30f;
    if (l1 < clen) sc1 = tanhf(Qs[l1] + s_h + batt);
    if (l2 < clen) sc2 = tanhf(Qs[l2] + s_h + batt);
    float mx = fmaxf(sc1, sc2);
    breduce<true>(&mx, 1, red, tid);

    float pe[9];
#pragma unroll
    for (int q = 0; q < 9; ++q) pe[q] = 0.f;
    int kd = 5 - h;
    if (l1 < clen) {
      float e = expf(sc1 - mx);
      pe[0] += e;
      for (int k = 0; k <= 4 - h; ++k) pe[1 + k] += e * Qs[(1 + k) * LL + l1];
#pragma unroll
      for (int c = 0; c < 3; ++c) pe[6 + c] += e * Qs[(7 + 6 * c + kd) * LL + l1];
    }
    if (l2 < clen) {
      float e = expf(sc2 - mx);
      pe[0] += e;
      for (int k = 0; k <= 4 - h; ++k) pe[1 + k] += e * Qs[(1 + k) * LL + l2];
#pragma unroll
      for (int c = 0; c < 3; ++c) pe[6 + c] += e * Qs[(7 + 6 * c + kd) * LL + l2];
    }
    breduce<false>(pe, 9, red, tid);

    float invS = 1.f / pe[0];
    for (int k = 0; k <= 4 - h; ++k)
      tcur[k] = pe[1 + k] * invS + tcur[k + 1] + beta[k];
#pragma unroll
    for (int c = 0; c < 3; ++c)
      rc[c] = pe[6 + c] * invS + rc[c] + gam[c * 6 + kd];
  }
  if (tid < 3) out[b * 3 + tid] = rc[tid] + b_out[tid];
}

extern "C" void kernel_launch(void* const* d_in, const int* in_sizes, int n_in,
                              void* d_out, int out_size, void* d_ws, size_t ws_size,
                              hipStream_t stream)
{
  const int*   ctx_ids = (const int*)d_in[0];
  const int*   tgt_ids = (const int*)d_in[1];
  const int*   ctx_len = (const int*)d_in[2];
  const int*   tgt_len = (const int*)d_in[3];
  const int*   toff    = (const int*)d_in[4];
  const float* emb     = (const float*)d_in[5];
  const float* Wl      = (const float*)d_in[6];
  const float* bl      = (const float*)d_in[7];
  const float* wat     = (const float*)d_in[8];
  const float* bat     = (const float*)d_in[9];
  const float* Wo      = (const float*)d_in[10];
  const float* bo      = (const float*)d_in[11];
  float* ws = (float*)d_ws;
  float* Mt = ws;                 // 1024*32
  float* Mc = ws + 32768;         // 32*1024
  float* Q  = ws + 65536;         // 64*25*512
  float* outp = (float*)d_out;

  hipLaunchKernelGGL(k_init, dim3(4), dim3(256), 0, stream, wat, Wo, Mt, Mc);
  for (int s = 1; s <= 6; ++s) {
    int i0 = (s <= 5) ? s : -1;
    int o0 = (s <= 5) ? (1 + s) : -1;
    int i1 = 6 + s,  o1 = (s <= 5) ? (7 + s)  : 25;
    int i2 = 12 + s, o2 = (s <= 5) ? (13 + s) : 26;
    int i3 = 18 + s, o3 = (s <= 5) ? (19 + s) : 27;
    hipLaunchKernelGGL(k_chain, dim3(256), dim3(256), 0, stream,
                       Wl, Mt, Mc, i0, i1, i2, i3, o0, o1, o2, o3);
  }
  hipLaunchKernelGGL(k_gemm, dim3(512), dim3(256), 0, stream,
                     ctx_ids, ctx_len, toff, emb, Mt, Q);
  hipLaunchKernelGGL(k_hop, dim3(64), dim3(256), 0, stream,
                     tgt_ids, tgt_len, ctx_len, emb, bl, bat, bo, Mc, Q, outp);
}